// Round 3
// baseline (81.174 us; speedup 1.0000x reference)
//
#include <hip/hip_runtime.h>
#include <math.h>

#define N_NODES 100000
#define NEDGE 64
#define NFEAT 11
#define EFEAT 30
#define MEM 64
#define TD 16
#define MSGIN 174
#define G3 192
#define NB_BULK 256
#define NSLOT 128

// ws layout (bytes)
#define WS_PART_OFF   0
#define WS_STATES_OFF ((size_t)NB_BULK*12*sizeof(double))                 // 24576
#define WS_DONE_OFF   (WS_STATES_OFF + (size_t)NSLOT*MEM*sizeof(float))   // +32768 = 57344
#define WS_NUMS_OFF   (WS_DONE_OFF + 80*sizeof(int))                      // +320  = 57664
#define WS_DENS_OFF   (WS_NUMS_OFF + (size_t)NSLOT*MEM*sizeof(float))     // +32768 = 90432
#define WS_C0_OFF     (WS_DENS_OFF + (size_t)NSLOT*sizeof(float))         // +512  = 90944

__device__ __forceinline__ float sigmoidf_(float x) { return 1.f/(1.f+expf(-x)); }

__global__ __launch_bounds__(256) void k_main(
    const float* __restrict__ nf, const int* __restrict__ src, const int* __restrict__ dst,
    const float* __restrict__ ts, const float* __restrict__ ef,
    const float* __restrict__ Wnp, const float* __restrict__ bnp,
    const float* __restrict__ Wmsg, const float* __restrict__ bmsg,
    const float* __restrict__ Wih, const float* __restrict__ Whh,
    const float* __restrict__ bih, const float* __restrict__ bhh,
    const float* __restrict__ w0, const float* __restrict__ b0,
    const float* __restrict__ tW, const float* __restrict__ tB,
    const float* __restrict__ Wg, const float* __restrict__ bg,
    const float* __restrict__ Wp, const float* __restrict__ bp,
    double* __restrict__ partials, float* __restrict__ states,
    int* __restrict__ done, int* __restrict__ cnt,
    float* __restrict__ numS, float* __restrict__ denS, float* __restrict__ c0S,
    float* __restrict__ out)
{
  int t = threadIdx.x;
  int bid = blockIdx.x;

  // ================= bulk blocks: E = sum(e), S[k] = sum(e*nf[:,k]) =================
  if (bid >= NEDGE && bid < NEDGE + NB_BULK) {
    __shared__ float sG[NFEAT];
    __shared__ float sCl;
    __shared__ float sTile[256*NFEAT];
    __shared__ float sW[4][12];
    int b = bid - NEDGE;
    if (t < NFEAT) { float a = 0.f; for (int j=0;j<MEM;j++) a += Wnp[t*MEM+j]*Wg[j]; sG[t] = a; }
    if (t == NFEAT) { float a = bg[0]; for (int j=0;j<MEM;j++) a += bnp[j]*Wg[j]; sCl = a; }
    __syncthreads();
    float accE = 0.f, accS[NFEAT];
    #pragma unroll
    for (int k=0;k<NFEAT;k++) accS[k]=0.f;
    for (int base = b*256; base < N_NODES; base += NB_BULK*256) {
      int nrows = min(256, N_NODES - base);
      for (int i = t; i < nrows*NFEAT; i += 256) sTile[i] = nf[(long)base*NFEAT + i];
      __syncthreads();
      if (t < nrows) {
        float x[NFEAT];
        #pragma unroll
        for (int k=0;k<NFEAT;k++) x[k] = sTile[t*NFEAT+k];
        float l = sCl;
        #pragma unroll
        for (int k=0;k<NFEAT;k++) l += x[k]*sG[k];
        float e = expf(l);
        accE += e;
        #pragma unroll
        for (int k=0;k<NFEAT;k++) accS[k] += e*x[k];
      }
      __syncthreads();
    }
    #pragma unroll
    for (int off=32; off; off>>=1) {
      accE += __shfl_down(accE, off);
      #pragma unroll
      for (int k=0;k<NFEAT;k++) accS[k] += __shfl_down(accS[k], off);
    }
    int wv = t>>6;
    if ((t&63)==0) { sW[wv][0]=accE; for (int k=0;k<NFEAT;k++) sW[wv][1+k]=accS[k]; }
    __syncthreads();
    if (t < 12) {
      double d = (double)sW[0][t] + (double)sW[1][t] + (double)sW[2][t] + (double)sW[3][t];
      partials[b*12 + t] = d;
    }
    __syncthreads();
    __threadfence();
    if (t == 0) __hip_atomic_fetch_add(cnt, 1, __ATOMIC_RELEASE, __HIP_MEMORY_SCOPE_AGENT);
    return;
  }

  // ================= final block: wait for all producers, combine =================
  if (bid == NEDGE + NB_BULK + NSLOT) {
    __shared__ double sTot[12], sC0[12], sDen;
    __shared__ double sT[MEM];
    if (t < 64) {
      while (__hip_atomic_load(cnt, __ATOMIC_ACQUIRE, __HIP_MEMORY_SCOPE_AGENT) < NB_BULK + NSLOT)
        __builtin_amdgcn_s_sleep(8);
    }
    __syncthreads();
    if (t < 12) {
      double d = 0.0;
      for (int b = 0; b < NB_BULK; b++) d += partials[b*12 + t];
      sTot[t] = d;
    }
    if (t >= 16 && t < 28) {
      int k = t - 16;
      double d = 0.0;
      for (int s2 = 0; s2 < NSLOT; s2++) d += (double)c0S[s2*12 + k];
      sC0[k] = d;
    }
    if (t == 28) {
      double d = 0.0;
      for (int s2 = 0; s2 < NSLOT; s2++) d += (double)denS[s2];
      sDen = d;
    }
    double n1 = 0.0;
    if (t < 64) {
      for (int s2 = 0; s2 < NSLOT; s2++) n1 += (double)numS[s2*MEM + t];
    }
    __syncthreads();
    if (t < 64) {
      double Eall = sTot[0] - sC0[0];
      double a = Eall * (double)bnp[t];
      #pragma unroll
      for (int k=0;k<NFEAT;k++) a += (sTot[1+k] - sC0[1+k])*(double)Wnp[k*MEM+t];
      sT[t] = a;
    }
    __syncthreads();
    if (t < 64) {
      double Eall = sTot[0] - sC0[0];
      double a = 0.0;
      for (int m=0;m<MEM;m++) a += sT[m]*(double)Wp[m*MEM+t];
      a += Eall*(double)bp[t] + n1;
      out[t] = (float)(a/(Eall + sDen));
    }
    return;
  }

  // ================= edge blocks (bid<64) and slot blocks (192..319) =================
  __shared__ int sEp[128], sMap[128], sFirst[128];
  if (t < 64) sEp[t] = src[t];
  else if (t < 128) sEp[t] = dst[t-64];
  __syncthreads();
  if (t < 128) {
    int id = sEp[t]; int fo = t; int fe = t & 63;
    for (int i = 0; i < 128; i++) {
      if (sEp[i] == id) { if (i < fo) fo = i; int ei = i & 63; if (ei < fe) fe = ei; }
    }
    sMap[t] = fo; sFirst[t] = fe;
  }
  __syncthreads();

  if (bid < NEDGE) {
    // ---------------- edge block ----------------
    __shared__ float sX[176];
    __shared__ float sMsg[MEM];
    __shared__ float sGi[G3], sGhs[G3], sGhd[G3];
    __shared__ float sNewS[MEM];
    int e = bid;
    int ss = sMap[e], dd = sMap[64+e];

    if (t < e) {
      bool c = (sMap[t]==ss) || (sMap[t]==dd) || (sMap[64+t]==ss) || (sMap[64+t]==dd);
      if (c) {
        while (!__hip_atomic_load(&done[t], __ATOMIC_ACQUIRE, __HIP_MEMORY_SCOPE_AGENT))
          __builtin_amdgcn_s_sleep(2);
      }
    }
    __syncthreads();

    bool initS = (sFirst[ss] == e);
    bool initD = (sFirst[dd] == e);
    if (t < 64) {
      float v;
      if (initS) {
        const float* row = nf + (long)sEp[ss]*NFEAT;
        v = bnp[t];
        #pragma unroll
        for (int k = 0; k < NFEAT; k++) v += row[k]*Wnp[k*MEM + t];
      } else {
        v = __hip_atomic_load(&states[ss*MEM + t], __ATOMIC_RELAXED, __HIP_MEMORY_SCOPE_AGENT);
      }
      sX[t] = v;
    } else if (t < 128) {
      int j = t - 64; float v;
      if (initD) {
        const float* row = nf + (long)sEp[dd]*NFEAT;
        v = bnp[j];
        #pragma unroll
        for (int k = 0; k < NFEAT; k++) v += row[k]*Wnp[k*MEM + j];
      } else {
        v = __hip_atomic_load(&states[dd*MEM + j], __ATOMIC_RELAXED, __HIP_MEMORY_SCOPE_AGENT);
      }
      sX[t] = v;
    } else if (t < 158) {
      sX[t] = ef[e*EFEAT + (t-128)];
    } else if (t < 174) {
      int q = t - 158; float tt = ts[e];
      sX[t] = (q == 0) ? (tt*w0[0] + b0[0]) : sinf(tt*tW[q-1] + tB[q-1]);
    } else if (t < 176) sX[t] = 0.f;
    __syncthreads();

    {
      int mj = t >> 2, mg = t & 3, mk0 = mg*44;
      float w[44];
      #pragma unroll
      for (int kk = 0; kk < 44; kk++) {
        int k = mk0 + kk;
        w[kk] = (k < MSGIN) ? Wmsg[k*MEM + mj] : 0.f;
      }
      float a0=0.f,a1=0.f,a2=0.f,a3=0.f;
      #pragma unroll
      for (int kk=0; kk<44; kk+=4) {
        a0 += w[kk]  * sX[mk0+kk];
        a1 += w[kk+1]* sX[mk0+kk+1];
        a2 += w[kk+2]* sX[mk0+kk+2];
        a3 += w[kk+3]* sX[mk0+kk+3];
      }
      float a = (a0+a1)+(a2+a3);
      a += __shfl_xor(a,1);
      a += __shfl_xor(a,2);
      if (mg == 0) sMsg[mj] = fmaxf(a + bmsg[mj], 0.f);
    }
    __syncthreads();

    if (t < G3) {
      const float4* wi4 = (const float4*)(Wih + t*MEM);
      const float4* wh4 = (const float4*)(Whh + t*MEM);
      float a0=0.f,a1=0.f,a2=0.f,a3=0.f;
      float b0v=0.f,b1v=0.f,b2v=0.f,b3v=0.f;
      float c0=0.f,c1=0.f,c2=0.f,c3=0.f;
      #pragma unroll
      for (int k = 0; k < MEM; k += 4) {
        float4 vi = wi4[k>>2];
        float4 vh = wh4[k>>2];
        a0 += vi.x*sMsg[k];   a1 += vi.y*sMsg[k+1];   a2 += vi.z*sMsg[k+2];   a3 += vi.w*sMsg[k+3];
        b0v+= vh.x*sX[k];     b1v+= vh.y*sX[k+1];     b2v+= vh.z*sX[k+2];     b3v+= vh.w*sX[k+3];
        c0 += vh.x*sX[64+k];  c1 += vh.y*sX[64+k+1];  c2 += vh.z*sX[64+k+2];  c3 += vh.w*sX[64+k+3];
      }
      sGi[t]  = (a0+a1)+(a2+a3) + bih[t];
      sGhs[t] = (b0v+b1v)+(b2v+b3v) + bhh[t];
      sGhd[t] = (c0+c1)+(c2+c3) + bhh[t];
    }
    __syncthreads();

    if (ss != dd) {
      if (t < 128) {
        int j = t & 63;
        bool iss = t < 64;
        float h = sX[t];
        const float* gh = iss ? sGhs : sGhd;
        float r = sigmoidf_(sGi[j] + gh[j]);
        float z = sigmoidf_(sGi[64+j] + gh[64+j]);
        float n = tanhf(sGi[128+j] + r*gh[128+j]);
        float hn = (1.f - z)*n + z*h;
        int slot = iss ? ss : dd;
        __hip_atomic_store(&states[slot*MEM + j], hn, __ATOMIC_RELAXED, __HIP_MEMORY_SCOPE_AGENT);
      }
    } else {
      if (t < 64) {
        float h = sX[t];
        float r = sigmoidf_(sGi[t] + sGhs[t]);
        float z = sigmoidf_(sGi[64+t] + sGhs[64+t]);
        float n = tanhf(sGi[128+t] + r*sGhs[128+t]);
        sNewS[t] = (1.f - z)*n + z*h;
      }
      __syncthreads();
      if (t < G3) {
        const float4* wh4 = (const float4*)(Whh + t*MEM);
        float b0v=0.f,b1v=0.f,b2v=0.f,b3v=0.f;
        #pragma unroll
        for (int k = 0; k < MEM; k += 4) {
          float4 vh = wh4[k>>2];
          b0v += vh.x*sNewS[k];  b1v += vh.y*sNewS[k+1];
          b2v += vh.z*sNewS[k+2]; b3v += vh.w*sNewS[k+3];
        }
        sGhd[t] = (b0v+b1v)+(b2v+b3v) + bhh[t];
      }
      __syncthreads();
      if (t < 64) {
        float h = sNewS[t];
        float r = sigmoidf_(sGi[t] + sGhd[t]);
        float z = sigmoidf_(sGi[64+t] + sGhd[64+t]);
        float n = tanhf(sGi[128+t] + r*sGhd[128+t]);
        float hn = (1.f - z)*n + z*h;
        __hip_atomic_store(&states[ss*MEM + t], hn, __ATOMIC_RELAXED, __HIP_MEMORY_SCOPE_AGENT);
      }
    }
    __threadfence();
    __syncthreads();
    if (t == 0) __hip_atomic_store(&done[e], 1, __ATOMIC_RELEASE, __HIP_MEMORY_SCOPE_AGENT);
    return;
  }

  // ---------------- slot block: per-canonical-slot readout ----------------
  {
    __shared__ float sHl[MEM];
    __shared__ int sLe;
    int s = bid - (NEDGE + NB_BULK);
    bool live = (sMap[s] == s);
    if (!live) {
      if (t < 64) numS[s*MEM + t] = 0.f;
      if (t == 64) denS[s] = 0.f;
      if (t >= 128 && t < 140) c0S[s*12 + (t-128)] = 0.f;
      __syncthreads();
      __threadfence();
      if (t == 0) __hip_atomic_fetch_add(cnt, 1, __ATOMIC_RELEASE, __HIP_MEMORY_SCOPE_AGENT);
      return;
    }
    if (t == 0) {
      int le = 0;
      for (int i = 0; i < 128; i++) if (sMap[i] == s) { int ei = i & 63; if (ei > le) le = ei; }
      sLe = le;
    }
    __syncthreads();
    if (t < 64) {
      int le = sLe;
      while (!__hip_atomic_load(&done[le], __ATOMIC_ACQUIRE, __HIP_MEMORY_SCOPE_AGENT))
        __builtin_amdgcn_s_sleep(2);
    }
    if (t < 64) {
      float h = __hip_atomic_load(&states[s*MEM + t], __ATOMIC_RELAXED, __HIP_MEMORY_SCOPE_AGENT);
      sHl[t] = h;
    }
    __syncthreads();
    if (t < 64) {
      float vv = sHl[t] * Wg[t];
      #pragma unroll
      for (int off=32; off; off>>=1) vv += __shfl_xor(vv, off);
      float e1 = expf(vv + bg[0]);
      float p = bp[t];
      #pragma unroll 8
      for (int m = 0; m < MEM; m++) p += sHl[m] * Wp[m*MEM + t];
      numS[s*MEM + t] = e1 * p;
      if (t == 0) denS[s] = e1;
    } else if (t >= 128 && t < 192) {
      int j = t - 128;
      const float* row = nf + (long)sEp[s]*NFEAT;
      float x[NFEAT];
      #pragma unroll
      for (int k=0;k<NFEAT;k++) x[k] = row[k];
      float h0 = bnp[j];
      #pragma unroll
      for (int k=0;k<NFEAT;k++) h0 += x[k]*Wnp[k*MEM + j];
      float vv = h0 * Wg[j];
      #pragma unroll
      for (int off=32; off; off>>=1) vv += __shfl_xor(vv, off);
      float e0 = expf(vv + bg[0]);
      if (j == 0) c0S[s*12] = e0;
      if (j < NFEAT) c0S[s*12 + 1 + j] = e0 * x[j];
    }
    __syncthreads();
    __threadfence();
    if (t == 0) __hip_atomic_fetch_add(cnt, 1, __ATOMIC_RELEASE, __HIP_MEMORY_SCOPE_AGENT);
    return;
  }
}

extern "C" void kernel_launch(void* const* d_in, const int* in_sizes, int n_in,
                              void* d_out, int out_size, void* d_ws, size_t ws_size,
                              hipStream_t stream) {
  (void)in_sizes; (void)n_in; (void)out_size; (void)ws_size;
  const float* nf   = (const float*)d_in[0];
  const int*   src  = (const int*)d_in[1];
  const int*   dst  = (const int*)d_in[2];
  const float* ts   = (const float*)d_in[3];
  const float* ef   = (const float*)d_in[4];
  const float* Wnp  = (const float*)d_in[5];
  const float* bnp  = (const float*)d_in[6];
  const float* Wmsg = (const float*)d_in[7];
  const float* bmsg = (const float*)d_in[8];
  const float* Wih  = (const float*)d_in[9];
  const float* Whh  = (const float*)d_in[10];
  const float* bih  = (const float*)d_in[11];
  const float* bhh  = (const float*)d_in[12];
  const float* w0   = (const float*)d_in[13];
  const float* b0   = (const float*)d_in[14];
  const float* tW   = (const float*)d_in[15];
  const float* tB   = (const float*)d_in[16];
  const float* Wg   = (const float*)d_in[17];
  const float* bg   = (const float*)d_in[18];
  const float* Wp   = (const float*)d_in[19];
  const float* bp   = (const float*)d_in[20];

  double* partials = (double*)((char*)d_ws + WS_PART_OFF);
  float*  states   = (float*)((char*)d_ws + WS_STATES_OFF);
  int*    done     = (int*)((char*)d_ws + WS_DONE_OFF);
  int*    cnt      = done + 64;
  float*  numS     = (float*)((char*)d_ws + WS_NUMS_OFF);
  float*  denS     = (float*)((char*)d_ws + WS_DENS_OFF);
  float*  c0S      = (float*)((char*)d_ws + WS_C0_OFF);
  float*  out      = (float*)d_out;

  hipMemsetAsync(done, 0, 80*sizeof(int), stream);
  k_main<<<NEDGE + NB_BULK + NSLOT + 1, 256, 0, stream>>>(
      nf, src, dst, ts, ef, Wnp, bnp, Wmsg, bmsg,
      Wih, Whh, bih, bhh, w0, b0, tW, tB, Wg, bg, Wp, bp,
      partials, states, done, cnt, numS, denS, c0S, out);
}

// Round 4
// 53.605 us; speedup vs baseline: 1.5143x; 1.5143x over previous
//
#include <hip/hip_runtime.h>
#include <math.h>

#define N_NODES 100000
#define NEDGE 64
#define NFEAT 11
#define EFEAT 30
#define MEM 64
#define TD 16
#define MSGIN 174
#define G3 192
#define NB_BULK 392
#define NSLOT 128

// ws layout (bytes)
#define WS_PART_OFF   0
#define WS_STATES_OFF ((size_t)NB_BULK*12*sizeof(double))                   // 37632
#define WS_DONE_OFF   (WS_STATES_OFF + (size_t)NSLOT*MEM*sizeof(float))     // +32768
#define WS_NUMS_OFF   (WS_DONE_OFF + 80*sizeof(int))
#define WS_DENS_OFF   (WS_NUMS_OFF + (size_t)NSLOT*MEM*sizeof(float))
#define WS_C0_OFF     (WS_DENS_OFF + (size_t)NSLOT*sizeof(float))

__device__ __forceinline__ float sigmoidf_(float x) { return 1.f/(1.f+expf(-x)); }

// ================= k1: 64 edge blocks + 392 bulk blocks + 128 slot blocks =================
__global__ __launch_bounds__(256) void k_main(
    const float* __restrict__ nf, const int* __restrict__ src, const int* __restrict__ dst,
    const float* __restrict__ ts, const float* __restrict__ ef,
    const float* __restrict__ Wnp, const float* __restrict__ bnp,
    const float* __restrict__ Wmsg, const float* __restrict__ bmsg,
    const float* __restrict__ Wih, const float* __restrict__ Whh,
    const float* __restrict__ bih, const float* __restrict__ bhh,
    const float* __restrict__ w0, const float* __restrict__ b0,
    const float* __restrict__ tW, const float* __restrict__ tB,
    const float* __restrict__ Wg, const float* __restrict__ bg,
    const float* __restrict__ Wp, const float* __restrict__ bp,
    double* __restrict__ partials, float* __restrict__ states,
    int* __restrict__ done,
    float* __restrict__ numS, float* __restrict__ denS, float* __restrict__ c0S)
{
  int t = threadIdx.x;
  int bid = blockIdx.x;

  // ---------------- bulk blocks: one 256-row tile each ----------------
  if (bid >= NEDGE && bid < NEDGE + NB_BULK) {
    __shared__ float sG[NFEAT];
    __shared__ float sCl;
    __shared__ float sTile[256*NFEAT];
    __shared__ float sW[4][12];
    int b = bid - NEDGE;
    if (t < NFEAT) { float a = 0.f; for (int j=0;j<MEM;j++) a += Wnp[t*MEM+j]*Wg[j]; sG[t] = a; }
    if (t == NFEAT) { float a = bg[0]; for (int j=0;j<MEM;j++) a += bnp[j]*Wg[j]; sCl = a; }
    __syncthreads();
    float accE = 0.f, accS[NFEAT];
    #pragma unroll
    for (int k=0;k<NFEAT;k++) accS[k]=0.f;
    int base = b*256;
    if (base < N_NODES) {
      int nrows = min(256, N_NODES - base);
      for (int i = t; i < nrows*NFEAT; i += 256) sTile[i] = nf[(long)base*NFEAT + i];
      __syncthreads();
      if (t < nrows) {
        float x[NFEAT];
        #pragma unroll
        for (int k=0;k<NFEAT;k++) x[k] = sTile[t*NFEAT+k];
        float l = sCl;
        #pragma unroll
        for (int k=0;k<NFEAT;k++) l += x[k]*sG[k];
        float e = expf(l);
        accE += e;
        #pragma unroll
        for (int k=0;k<NFEAT;k++) accS[k] += e*x[k];
      }
    }
    #pragma unroll
    for (int off=32; off; off>>=1) {
      accE += __shfl_down(accE, off);
      #pragma unroll
      for (int k=0;k<NFEAT;k++) accS[k] += __shfl_down(accS[k], off);
    }
    int wv = t>>6;
    if ((t&63)==0) { sW[wv][0]=accE; for (int k=0;k<NFEAT;k++) sW[wv][1+k]=accS[k]; }
    __syncthreads();
    if (t < 12) {
      double d = (double)sW[0][t] + (double)sW[1][t] + (double)sW[2][t] + (double)sW[3][t];
      partials[b*12 + t] = d;   // visible to k_fin via kernel-boundary release
    }
    return;
  }

  // ---------------- edge blocks and slot blocks share endpoint maps ----------------
  __shared__ int sEp[128], sMap[128], sFirst[128];
  if (t < 64) sEp[t] = src[t];
  else if (t < 128) sEp[t] = dst[t-64];
  __syncthreads();
  if (t < 128) {
    int id = sEp[t]; int fo = t; int fe = t & 63;
    for (int i = 0; i < 128; i++) {
      if (sEp[i] == id) { if (i < fo) fo = i; int ei = i & 63; if (ei < fe) fe = ei; }
    }
    sMap[t] = fo; sFirst[t] = fe;
  }
  __syncthreads();

  if (bid < NEDGE) {
    // ---------------- edge block (R2-proven protocol) ----------------
    __shared__ float sX[176];
    __shared__ float sMsg[MEM];
    __shared__ float sGi[G3], sGhs[G3], sGhd[G3];
    __shared__ float sNewS[MEM];
    int e = bid;
    int ss = sMap[e], dd = sMap[64+e];

    if (t < e) {
      bool c = (sMap[t]==ss) || (sMap[t]==dd) || (sMap[64+t]==ss) || (sMap[64+t]==dd);
      if (c) {
        while (!__hip_atomic_load(&done[t], __ATOMIC_ACQUIRE, __HIP_MEMORY_SCOPE_AGENT))
          __builtin_amdgcn_s_sleep(2);
      }
    }
    __syncthreads();

    bool initS = (sFirst[ss] == e);
    bool initD = (sFirst[dd] == e);
    if (t < 64) {
      float v;
      if (initS) {
        const float* row = nf + (long)sEp[ss]*NFEAT;
        v = bnp[t];
        #pragma unroll
        for (int k = 0; k < NFEAT; k++) v += row[k]*Wnp[k*MEM + t];
      } else {
        v = __hip_atomic_load(&states[ss*MEM + t], __ATOMIC_RELAXED, __HIP_MEMORY_SCOPE_AGENT);
      }
      sX[t] = v;
    } else if (t < 128) {
      int j = t - 64; float v;
      if (initD) {
        const float* row = nf + (long)sEp[dd]*NFEAT;
        v = bnp[j];
        #pragma unroll
        for (int k = 0; k < NFEAT; k++) v += row[k]*Wnp[k*MEM + j];
      } else {
        v = __hip_atomic_load(&states[dd*MEM + j], __ATOMIC_RELAXED, __HIP_MEMORY_SCOPE_AGENT);
      }
      sX[t] = v;
    } else if (t < 158) {
      sX[t] = ef[e*EFEAT + (t-128)];
    } else if (t < 174) {
      int q = t - 158; float tt = ts[e];
      sX[t] = (q == 0) ? (tt*w0[0] + b0[0]) : sinf(tt*tW[q-1] + tB[q-1]);
    } else if (t < 176) sX[t] = 0.f;
    __syncthreads();

    {
      int mj = t >> 2, mg = t & 3, mk0 = mg*44;
      float w[44];
      #pragma unroll
      for (int kk = 0; kk < 44; kk++) {
        int k = mk0 + kk;
        w[kk] = (k < MSGIN) ? Wmsg[k*MEM + mj] : 0.f;
      }
      float a0=0.f,a1=0.f,a2=0.f,a3=0.f;
      #pragma unroll
      for (int kk=0; kk<44; kk+=4) {
        a0 += w[kk]  * sX[mk0+kk];
        a1 += w[kk+1]* sX[mk0+kk+1];
        a2 += w[kk+2]* sX[mk0+kk+2];
        a3 += w[kk+3]* sX[mk0+kk+3];
      }
      float a = (a0+a1)+(a2+a3);
      a += __shfl_xor(a,1);
      a += __shfl_xor(a,2);
      if (mg == 0) sMsg[mj] = fmaxf(a + bmsg[mj], 0.f);
    }
    __syncthreads();

    if (t < G3) {
      const float4* wi4 = (const float4*)(Wih + t*MEM);
      const float4* wh4 = (const float4*)(Whh + t*MEM);
      float a0=0.f,a1=0.f,a2=0.f,a3=0.f;
      float b0v=0.f,b1v=0.f,b2v=0.f,b3v=0.f;
      float c0=0.f,c1=0.f,c2=0.f,c3=0.f;
      #pragma unroll
      for (int k = 0; k < MEM; k += 4) {
        float4 vi = wi4[k>>2];
        float4 vh = wh4[k>>2];
        a0 += vi.x*sMsg[k];   a1 += vi.y*sMsg[k+1];   a2 += vi.z*sMsg[k+2];   a3 += vi.w*sMsg[k+3];
        b0v+= vh.x*sX[k];     b1v+= vh.y*sX[k+1];     b2v+= vh.z*sX[k+2];     b3v+= vh.w*sX[k+3];
        c0 += vh.x*sX[64+k];  c1 += vh.y*sX[64+k+1];  c2 += vh.z*sX[64+k+2];  c3 += vh.w*sX[64+k+3];
      }
      sGi[t]  = (a0+a1)+(a2+a3) + bih[t];
      sGhs[t] = (b0v+b1v)+(b2v+b3v) + bhh[t];
      sGhd[t] = (c0+c1)+(c2+c3) + bhh[t];
    }
    __syncthreads();

    if (ss != dd) {
      if (t < 128) {
        int j = t & 63;
        bool iss = t < 64;
        float h = sX[t];
        const float* gh = iss ? sGhs : sGhd;
        float r = sigmoidf_(sGi[j] + gh[j]);
        float z = sigmoidf_(sGi[64+j] + gh[64+j]);
        float n = tanhf(sGi[128+j] + r*gh[128+j]);
        float hn = (1.f - z)*n + z*h;
        int slot = iss ? ss : dd;
        __hip_atomic_store(&states[slot*MEM + j], hn, __ATOMIC_RELAXED, __HIP_MEMORY_SCOPE_AGENT);
      }
    } else {
      if (t < 64) {
        float h = sX[t];
        float r = sigmoidf_(sGi[t] + sGhs[t]);
        float z = sigmoidf_(sGi[64+t] + sGhs[64+t]);
        float n = tanhf(sGi[128+t] + r*sGhs[128+t]);
        sNewS[t] = (1.f - z)*n + z*h;
      }
      __syncthreads();
      if (t < G3) {
        const float4* wh4 = (const float4*)(Whh + t*MEM);
        float b0v=0.f,b1v=0.f,b2v=0.f,b3v=0.f;
        #pragma unroll
        for (int k = 0; k < MEM; k += 4) {
          float4 vh = wh4[k>>2];
          b0v += vh.x*sNewS[k];  b1v += vh.y*sNewS[k+1];
          b2v += vh.z*sNewS[k+2]; b3v += vh.w*sNewS[k+3];
        }
        sGhd[t] = (b0v+b1v)+(b2v+b3v) + bhh[t];
      }
      __syncthreads();
      if (t < 64) {
        float h = sNewS[t];
        float r = sigmoidf_(sGi[t] + sGhd[t]);
        float z = sigmoidf_(sGi[64+t] + sGhd[64+t]);
        float n = tanhf(sGi[128+t] + r*sGhd[128+t]);
        float hn = (1.f - z)*n + z*h;
        __hip_atomic_store(&states[ss*MEM + t], hn, __ATOMIC_RELAXED, __HIP_MEMORY_SCOPE_AGENT);
      }
    }
    __threadfence();
    __syncthreads();
    if (t == 0) __hip_atomic_store(&done[e], 1, __ATOMIC_RELEASE, __HIP_MEMORY_SCOPE_AGENT);
    return;
  }

  // ---------------- slot blocks: per-canonical-slot readout (no fences; k-boundary publishes) ----------------
  {
    __shared__ float sHl[MEM];
    __shared__ int sLe;
    int s = bid - (NEDGE + NB_BULK);
    bool live = (sMap[s] == s);
    if (!live) {
      if (t < 64) numS[s*MEM + t] = 0.f;
      if (t == 64) denS[s] = 0.f;
      if (t >= 128 && t < 140) c0S[s*12 + (t-128)] = 0.f;
      return;
    }
    if (t == 0) {
      int le = 0;
      for (int i = 0; i < 128; i++) if (sMap[i] == s) { int ei = i & 63; if (ei > le) le = ei; }
      sLe = le;
    }
    __syncthreads();
    if (t < 64) {
      int le = sLe;
      while (!__hip_atomic_load(&done[le], __ATOMIC_ACQUIRE, __HIP_MEMORY_SCOPE_AGENT))
        __builtin_amdgcn_s_sleep(2);
      sHl[t] = __hip_atomic_load(&states[s*MEM + t], __ATOMIC_RELAXED, __HIP_MEMORY_SCOPE_AGENT);
    }
    __syncthreads();
    if (t < 64) {
      float vv = sHl[t] * Wg[t];
      #pragma unroll
      for (int off=32; off; off>>=1) vv += __shfl_xor(vv, off);
      float e1 = expf(vv + bg[0]);
      float p = bp[t];
      #pragma unroll 8
      for (int m = 0; m < MEM; m++) p += sHl[m] * Wp[m*MEM + t];
      numS[s*MEM + t] = e1 * p;
      if (t == 0) denS[s] = e1;
    } else if (t >= 128 && t < 192) {
      int j = t - 128;
      const float* row = nf + (long)sEp[s]*NFEAT;
      float x[NFEAT];
      #pragma unroll
      for (int k=0;k<NFEAT;k++) x[k] = row[k];
      float h0 = bnp[j];
      #pragma unroll
      for (int k=0;k<NFEAT;k++) h0 += x[k]*Wnp[k*MEM + j];
      float vv = h0 * Wg[j];
      #pragma unroll
      for (int off=32; off; off>>=1) vv += __shfl_xor(vv, off);
      float e0 = expf(vv + bg[0]);
      if (j == 0) c0S[s*12] = e0;
      if (j < NFEAT) c0S[s*12 + 1 + j] = e0 * x[j];
    }
    return;
  }
}

// ================= k2: parallel combine =================
__global__ __launch_bounds__(256) void k_fin(
    const float* __restrict__ Wnp, const float* __restrict__ bnp,
    const float* __restrict__ Wp, const float* __restrict__ bp,
    const double* __restrict__ partials, const float* __restrict__ numS,
    const float* __restrict__ denS, const float* __restrict__ c0S,
    float* __restrict__ out)
{
  __shared__ double sA[4][13];
  __shared__ double sTot[12];
  __shared__ double sC[13];
  __shared__ double sN[4][64];
  __shared__ double sT[MEM];
  int t = threadIdx.x, lane = t & 63, wv = t >> 6;

  // ---- partials: NB_BULK x 12 doubles, two rows per thread ----
  double v[12];
  #pragma unroll
  for (int k=0;k<12;k++) {
    double a = partials[t*12 + k];
    if (t + 256 < NB_BULK) a += partials[(t+256)*12 + k];
    v[k] = a;
  }
  #pragma unroll
  for (int off=32; off; off>>=1) {
    #pragma unroll
    for (int k=0;k<12;k++) v[k] += __shfl_down(v[k], off);
  }
  if (lane == 0) { for (int k=0;k<12;k++) sA[wv][k] = v[k]; }

  // ---- numS: 128 x 64 floats, strided groups ----
  {
    double a = 0.0;
    for (int s = wv; s < NSLOT; s += 4) a += (double)numS[s*MEM + lane];
    sN[wv][lane] = a;
  }
  __syncthreads();
  if (t < 12) sTot[t] = sA[0][t] + sA[1][t] + sA[2][t] + sA[3][t];
  __syncthreads();

  // ---- c0S (128 x 12) + denS (128) ----
  {
    double c[13];
    if (t < NSLOT) {
      #pragma unroll
      for (int k=0;k<12;k++) c[k] = (double)c0S[t*12 + k];
      c[12] = (double)denS[t];
    } else {
      #pragma unroll
      for (int k=0;k<13;k++) c[k] = 0.0;
    }
    #pragma unroll
    for (int off=32; off; off>>=1) {
      #pragma unroll
      for (int k=0;k<13;k++) c[k] += __shfl_down(c[k], off);
    }
    if (lane == 0 && wv < 2) { for (int k=0;k<13;k++) sA[wv][k] = c[k]; }
  }
  __syncthreads();
  if (t < 13) sC[t] = sA[0][t] + sA[1][t];
  __syncthreads();

  if (t < MEM) {
    double Eall = sTot[0] - sC[0];
    double a = Eall * (double)bnp[t];
    #pragma unroll
    for (int k=0;k<NFEAT;k++) a += (sTot[1+k] - sC[1+k])*(double)Wnp[k*MEM+t];
    sT[t] = a;
  }
  __syncthreads();
  if (t < MEM) {
    double Eall = sTot[0] - sC[0];
    double n1 = sN[0][t] + sN[1][t] + sN[2][t] + sN[3][t];
    double a = 0.0;
    for (int m=0;m<MEM;m++) a += sT[m]*(double)Wp[m*MEM+t];
    a += Eall*(double)bp[t] + n1;
    out[t] = (float)(a/(Eall + sC[12]));
  }
}

extern "C" void kernel_launch(void* const* d_in, const int* in_sizes, int n_in,
                              void* d_out, int out_size, void* d_ws, size_t ws_size,
                              hipStream_t stream) {
  (void)in_sizes; (void)n_in; (void)out_size; (void)ws_size;
  const float* nf   = (const float*)d_in[0];
  const int*   src  = (const int*)d_in[1];
  const int*   dst  = (const int*)d_in[2];
  const float* ts   = (const float*)d_in[3];
  const float* ef   = (const float*)d_in[4];
  const float* Wnp  = (const float*)d_in[5];
  const float* bnp  = (const float*)d_in[6];
  const float* Wmsg = (const float*)d_in[7];
  const float* bmsg = (const float*)d_in[8];
  const float* Wih  = (const float*)d_in[9];
  const float* Whh  = (const float*)d_in[10];
  const float* bih  = (const float*)d_in[11];
  const float* bhh  = (const float*)d_in[12];
  const float* w0   = (const float*)d_in[13];
  const float* b0   = (const float*)d_in[14];
  const float* tW   = (const float*)d_in[15];
  const float* tB   = (const float*)d_in[16];
  const float* Wg   = (const float*)d_in[17];
  const float* bg   = (const float*)d_in[18];
  const float* Wp   = (const float*)d_in[19];
  const float* bp   = (const float*)d_in[20];

  double* partials = (double*)((char*)d_ws + WS_PART_OFF);
  float*  states   = (float*)((char*)d_ws + WS_STATES_OFF);
  int*    done     = (int*)((char*)d_ws + WS_DONE_OFF);
  float*  numS     = (float*)((char*)d_ws + WS_NUMS_OFF);
  float*  denS     = (float*)((char*)d_ws + WS_DENS_OFF);
  float*  c0S      = (float*)((char*)d_ws + WS_C0_OFF);
  float*  out      = (float*)d_out;

  hipMemsetAsync(done, 0, NEDGE*sizeof(int), stream);
  k_main<<<NEDGE + NB_BULK + NSLOT, 256, 0, stream>>>(
      nf, src, dst, ts, ef, Wnp, bnp, Wmsg, bmsg,
      Wih, Whh, bih, bhh, w0, b0, tW, tB, Wg, bg, Wp, bp,
      partials, states, done, numS, denS, c0S);
  k_fin<<<1, 256, 0, stream>>>(Wnp, bnp, Wp, bp, partials, numS, denS, c0S, out);
}

// Round 5
// 50.767 us; speedup vs baseline: 1.5990x; 1.0559x over previous
//
#include <hip/hip_runtime.h>
#include <math.h>

#define N_NODES 100000
#define NEDGE 64
#define NFEAT 11
#define EFEAT 30
#define MEM 64
#define TD 16
#define MSGIN 174
#define G3 192
#define NB_BULK 391
#define NSLOT 128

// ws layout (bytes)
#define WS_PART_OFF   0
#define WS_STATES_OFF ((size_t)NB_BULK*12*sizeof(double))                   // 37536
#define WS_DONE_OFF   (WS_STATES_OFF + (size_t)NSLOT*MEM*sizeof(float))     // +32768

__device__ __forceinline__ float sigmoidf_(float x) { return 1.f/(1.f+expf(-x)); }

// ================= k1: 64 edge blocks + 391 bulk blocks =================
__global__ __launch_bounds__(256) void k_main(
    const float* __restrict__ nf, const int* __restrict__ src, const int* __restrict__ dst,
    const float* __restrict__ ts, const float* __restrict__ ef,
    const float* __restrict__ Wnp, const float* __restrict__ bnp,
    const float* __restrict__ Wmsg, const float* __restrict__ bmsg,
    const float* __restrict__ Wih, const float* __restrict__ Whh,
    const float* __restrict__ bih, const float* __restrict__ bhh,
    const float* __restrict__ w0, const float* __restrict__ b0,
    const float* __restrict__ tW, const float* __restrict__ tB,
    const float* __restrict__ Wg, const float* __restrict__ bg,
    double* __restrict__ partials, float* __restrict__ states,
    int* __restrict__ done)
{
  int t = threadIdx.x;
  int bid = blockIdx.x;

  // ---------------- bulk blocks: one 256-row tile each ----------------
  if (bid >= NEDGE) {
    __shared__ float sG[NFEAT];
    __shared__ float sCl;
    __shared__ float sTile[256*NFEAT];
    __shared__ float sW[4][12];
    int b = bid - NEDGE;
    if (t < NFEAT) { float a = 0.f; for (int j=0;j<MEM;j++) a += Wnp[t*MEM+j]*Wg[j]; sG[t] = a; }
    if (t == NFEAT) { float a = bg[0]; for (int j=0;j<MEM;j++) a += bnp[j]*Wg[j]; sCl = a; }
    __syncthreads();
    float accE = 0.f, accS[NFEAT];
    #pragma unroll
    for (int k=0;k<NFEAT;k++) accS[k]=0.f;
    int base = b*256;
    {
      int nrows = min(256, N_NODES - base);
      for (int i = t; i < nrows*NFEAT; i += 256) sTile[i] = nf[(long)base*NFEAT + i];
      __syncthreads();
      if (t < nrows) {
        float x[NFEAT];
        #pragma unroll
        for (int k=0;k<NFEAT;k++) x[k] = sTile[t*NFEAT+k];
        float l = sCl;
        #pragma unroll
        for (int k=0;k<NFEAT;k++) l += x[k]*sG[k];
        float e = expf(l);
        accE += e;
        #pragma unroll
        for (int k=0;k<NFEAT;k++) accS[k] += e*x[k];
      }
    }
    #pragma unroll
    for (int off=32; off; off>>=1) {
      accE += __shfl_down(accE, off);
      #pragma unroll
      for (int k=0;k<NFEAT;k++) accS[k] += __shfl_down(accS[k], off);
    }
    int wv = t>>6;
    if ((t&63)==0) { sW[wv][0]=accE; for (int k=0;k<NFEAT;k++) sW[wv][1+k]=accS[k]; }
    __syncthreads();
    if (t < 12) {
      double d = (double)sW[0][t] + (double)sW[1][t] + (double)sW[2][t] + (double)sW[3][t];
      partials[b*12 + t] = d;   // published to k_fin at kernel boundary
    }
    return;
  }

  // ---------------- edge block (R2-proven protocol, verbatim) ----------------
  __shared__ int sEp[128], sMap[128], sFirst[128];
  __shared__ float sX[176];
  __shared__ float sMsg[MEM];
  __shared__ float sGi[G3], sGhs[G3], sGhd[G3];
  __shared__ float sNewS[MEM];

  if (t < 64) sEp[t] = src[t];
  else if (t < 128) sEp[t] = dst[t-64];
  __syncthreads();
  if (t < 128) {
    int id = sEp[t]; int fo = t; int fe = t & 63;
    for (int i = 0; i < 128; i++) {
      if (sEp[i] == id) { if (i < fo) fo = i; int ei = i & 63; if (ei < fe) fe = ei; }
    }
    sMap[t] = fo; sFirst[t] = fe;
  }
  __syncthreads();

  int e = bid;
  int ss = sMap[e], dd = sMap[64+e];

  if (t < e) {
    bool c = (sMap[t]==ss) || (sMap[t]==dd) || (sMap[64+t]==ss) || (sMap[64+t]==dd);
    if (c) {
      while (!__hip_atomic_load(&done[t], __ATOMIC_ACQUIRE, __HIP_MEMORY_SCOPE_AGENT))
        __builtin_amdgcn_s_sleep(2);
    }
  }
  __syncthreads();

  bool initS = (sFirst[ss] == e);
  bool initD = (sFirst[dd] == e);
  if (t < 64) {
    float v;
    if (initS) {
      const float* row = nf + (long)sEp[ss]*NFEAT;
      v = bnp[t];
      #pragma unroll
      for (int k = 0; k < NFEAT; k++) v += row[k]*Wnp[k*MEM + t];
    } else {
      v = __hip_atomic_load(&states[ss*MEM + t], __ATOMIC_RELAXED, __HIP_MEMORY_SCOPE_AGENT);
    }
    sX[t] = v;
  } else if (t < 128) {
    int j = t - 64; float v;
    if (initD) {
      const float* row = nf + (long)sEp[dd]*NFEAT;
      v = bnp[j];
      #pragma unroll
      for (int k = 0; k < NFEAT; k++) v += row[k]*Wnp[k*MEM + j];
    } else {
      v = __hip_atomic_load(&states[dd*MEM + j], __ATOMIC_RELAXED, __HIP_MEMORY_SCOPE_AGENT);
    }
    sX[t] = v;
  } else if (t < 158) {
    sX[t] = ef[e*EFEAT + (t-128)];
  } else if (t < 174) {
    int q = t - 158; float tt = ts[e];
    sX[t] = (q == 0) ? (tt*w0[0] + b0[0]) : sinf(tt*tW[q-1] + tB[q-1]);
  } else if (t < 176) sX[t] = 0.f;
  __syncthreads();

  {
    int mj = t >> 2, mg = t & 3, mk0 = mg*44;
    float w[44];
    #pragma unroll
    for (int kk = 0; kk < 44; kk++) {
      int k = mk0 + kk;
      w[kk] = (k < MSGIN) ? Wmsg[k*MEM + mj] : 0.f;
    }
    float a0=0.f,a1=0.f,a2=0.f,a3=0.f;
    #pragma unroll
    for (int kk=0; kk<44; kk+=4) {
      a0 += w[kk]  * sX[mk0+kk];
      a1 += w[kk+1]* sX[mk0+kk+1];
      a2 += w[kk+2]* sX[mk0+kk+2];
      a3 += w[kk+3]* sX[mk0+kk+3];
    }
    float a = (a0+a1)+(a2+a3);
    a += __shfl_xor(a,1);
    a += __shfl_xor(a,2);
    if (mg == 0) sMsg[mj] = fmaxf(a + bmsg[mj], 0.f);
  }
  __syncthreads();

  if (t < G3) {
    const float4* wi4 = (const float4*)(Wih + t*MEM);
    const float4* wh4 = (const float4*)(Whh + t*MEM);
    float a0=0.f,a1=0.f,a2=0.f,a3=0.f;
    float b0v=0.f,b1v=0.f,b2v=0.f,b3v=0.f;
    float c0=0.f,c1=0.f,c2=0.f,c3=0.f;
    #pragma unroll
    for (int k = 0; k < MEM; k += 4) {
      float4 vi = wi4[k>>2];
      float4 vh = wh4[k>>2];
      a0 += vi.x*sMsg[k];   a1 += vi.y*sMsg[k+1];   a2 += vi.z*sMsg[k+2];   a3 += vi.w*sMsg[k+3];
      b0v+= vh.x*sX[k];     b1v+= vh.y*sX[k+1];     b2v+= vh.z*sX[k+2];     b3v+= vh.w*sX[k+3];
      c0 += vh.x*sX[64+k];  c1 += vh.y*sX[64+k+1];  c2 += vh.z*sX[64+k+2];  c3 += vh.w*sX[64+k+3];
    }
    sGi[t]  = (a0+a1)+(a2+a3) + bih[t];
    sGhs[t] = (b0v+b1v)+(b2v+b3v) + bhh[t];
    sGhd[t] = (c0+c1)+(c2+c3) + bhh[t];
  }
  __syncthreads();

  if (ss != dd) {
    if (t < 128) {
      int j = t & 63;
      bool iss = t < 64;
      float h = sX[t];
      const float* gh = iss ? sGhs : sGhd;
      float r = sigmoidf_(sGi[j] + gh[j]);
      float z = sigmoidf_(sGi[64+j] + gh[64+j]);
      float n = tanhf(sGi[128+j] + r*gh[128+j]);
      float hn = (1.f - z)*n + z*h;
      int slot = iss ? ss : dd;
      __hip_atomic_store(&states[slot*MEM + j], hn, __ATOMIC_RELAXED, __HIP_MEMORY_SCOPE_AGENT);
    }
  } else {
    if (t < 64) {
      float h = sX[t];
      float r = sigmoidf_(sGi[t] + sGhs[t]);
      float z = sigmoidf_(sGi[64+t] + sGhs[64+t]);
      float n = tanhf(sGi[128+t] + r*sGhs[128+t]);
      sNewS[t] = (1.f - z)*n + z*h;
    }
    __syncthreads();
    if (t < G3) {
      const float4* wh4 = (const float4*)(Whh + t*MEM);
      float b0v=0.f,b1v=0.f,b2v=0.f,b3v=0.f;
      #pragma unroll
      for (int k = 0; k < MEM; k += 4) {
        float4 vh = wh4[k>>2];
        b0v += vh.x*sNewS[k];  b1v += vh.y*sNewS[k+1];
        b2v += vh.z*sNewS[k+2]; b3v += vh.w*sNewS[k+3];
      }
      sGhd[t] = (b0v+b1v)+(b2v+b3v) + bhh[t];
    }
    __syncthreads();
    if (t < 64) {
      float h = sNewS[t];
      float r = sigmoidf_(sGi[t] + sGhd[t]);
      float z = sigmoidf_(sGi[64+t] + sGhd[64+t]);
      float n = tanhf(sGi[128+t] + r*sGhd[128+t]);
      float hn = (1.f - z)*n + z*h;
      __hip_atomic_store(&states[ss*MEM + t], hn, __ATOMIC_RELAXED, __HIP_MEMORY_SCOPE_AGENT);
    }
  }
  __threadfence();
  __syncthreads();
  if (t == 0) __hip_atomic_store(&done[e], 1, __ATOMIC_RELEASE, __HIP_MEMORY_SCOPE_AGENT);
}

// ================= k2: fully parallel readout + combine (1 block) =================
__global__ __launch_bounds__(256) void k_fin(
    const float* __restrict__ nf, const int* __restrict__ src, const int* __restrict__ dst,
    const float* __restrict__ Wnp, const float* __restrict__ bnp,
    const float* __restrict__ Wg, const float* __restrict__ bg,
    const float* __restrict__ Wp, const float* __restrict__ bp,
    const double* __restrict__ partials, const float* __restrict__ states,
    float* __restrict__ out)
{
  __shared__ float sH[NSLOT][MEM];      // 32 KB final states
  __shared__ float sWp[MEM][MEM];       // 16 KB
  __shared__ float sWnp[NFEAT][MEM];    // 2.75 KB
  __shared__ float sNF[NSLOT][12];      // nf rows of endpoints
  __shared__ int sEp[NSLOT], sMap[NSLOT];
  __shared__ float sWg[MEM], sBp[MEM], sBnp[MEM];
  __shared__ float sE0[4], sE1[4], sS0[4][NFEAT], sQ[4][MEM];
  __shared__ double sA[4][12];
  __shared__ double sTot[12];
  __shared__ double sM[MEM];
  __shared__ double sScal[3];           // E0tot, den1, (unused)

  int t = threadIdx.x, lane = t & 63, wv = t >> 6;
  float bg0 = bg[0];

  // ---- stage (parallel) ----
  if (t < 64) sEp[t] = src[t];
  else if (t < 128) sEp[t] = dst[t-64];
  if (t < MEM) { sWg[t] = Wg[t]; sBp[t] = bp[t]; sBnp[t] = bnp[t]; }
  for (int i = t; i < MEM*MEM; i += 256) sWp[i>>6][i&63] = Wp[i];
  for (int i = t; i < NFEAT*MEM; i += 256) sWnp[i>>6][i&63] = Wnp[i];
  for (int i = t; i < NSLOT*MEM; i += 256) sH[i>>6][i&63] = states[i];
  __syncthreads();
  if (t < 128) {
    int id = sEp[t]; int fo = t;
    for (int i = 0; i < 128; i++) if (sEp[i] == id) { fo = i; break; }
    sMap[t] = fo;
  }
  for (int i = t; i < NSLOT*NFEAT; i += 256) {
    int s = i / NFEAT, k = i - s*NFEAT;
    sNF[s][k] = nf[(long)sEp[s]*NFEAT + k];
  }
  __syncthreads();

  // ---- A: bulk partials reduction (391 x 12 doubles) ----
  {
    double v[12];
    #pragma unroll
    for (int k=0;k<12;k++) {
      double a = partials[t*12 + k];                       // t < 256 < 391
      if (t + 256 < NB_BULK) a += partials[(t+256)*12 + k];
      v[k] = a;
    }
    #pragma unroll
    for (int off=32; off; off>>=1) {
      #pragma unroll
      for (int k=0;k<12;k++) v[k] += __shfl_down(v[k], off);
    }
    if (lane == 0) { for (int k=0;k<12;k++) sA[wv][k] = v[k]; }
  }

  // ---- B: per-slot e0/e1/q (wave wv handles slots it*4+wv) ----
  {
    float accE0 = 0.f, accE1 = 0.f, accQ = 0.f, accS0[NFEAT];
    #pragma unroll
    for (int k=0;k<NFEAT;k++) accS0[k] = 0.f;
    for (int it = 0; it < 32; it++) {
      int s = it*4 + wv;
      bool used = (sMap[s] == s);
      // initial-memory gate logit
      float h0 = sBnp[lane];
      #pragma unroll
      for (int k=0;k<NFEAT;k++) h0 += sNF[s][k]*sWnp[k][lane];
      float v0 = h0 * sWg[lane];
      float v1 = sH[s][lane] * sWg[lane];
      #pragma unroll
      for (int off=32; off; off>>=1) { v0 += __shfl_xor(v0, off); v1 += __shfl_xor(v1, off); }
      float e0 = used ? expf(v0 + bg0) : 0.f;
      float e1 = used ? expf(v1 + bg0) : 0.f;
      accE0 += e0; accE1 += e1;
      #pragma unroll
      for (int k=0;k<NFEAT;k++) accS0[k] += e0*sNF[s][k];
      accQ += e1 * sH[s][lane];
    }
    if (lane == 0) { sE0[wv] = accE0; sE1[wv] = accE1; for (int k=0;k<NFEAT;k++) sS0[wv][k] = accS0[k]; }
    sQ[wv][lane] = accQ;
  }
  __syncthreads();

  if (t < 12) sTot[t] = sA[0][t] + sA[1][t] + sA[2][t] + sA[3][t];
  if (t == 12) sScal[0] = (double)sE0[0] + (double)sE0[1] + (double)sE0[2] + (double)sE0[3];
  if (t == 13) sScal[1] = (double)sE1[0] + (double)sE1[1] + (double)sE1[2] + (double)sE1[3];
  __syncthreads();

  // ---- C: combine in double ----
  if (t < MEM) {
    double Eall = sTot[0] - sScal[0];
    double a = Eall * (double)sBnp[t];
    #pragma unroll
    for (int k=0;k<NFEAT;k++) {
      double S0k = (double)sS0[0][k] + (double)sS0[1][k] + (double)sS0[2][k] + (double)sS0[3][k];
      a += (sTot[1+k] - S0k) * (double)sWnp[k][t];
    }
    double q = (double)sQ[0][t] + (double)sQ[1][t] + (double)sQ[2][t] + (double)sQ[3][t];
    sM[t] = a + q;
  }
  __syncthreads();
  if (t < MEM) {
    double Eall = sTot[0] - sScal[0];
    double den = Eall + sScal[1];
    double a = 0.0;
    for (int m=0;m<MEM;m++) a += sM[m] * (double)sWp[m][t];
    out[t] = (float)(a/den + (double)sBp[t]);
  }
}

extern "C" void kernel_launch(void* const* d_in, const int* in_sizes, int n_in,
                              void* d_out, int out_size, void* d_ws, size_t ws_size,
                              hipStream_t stream) {
  (void)in_sizes; (void)n_in; (void)out_size; (void)ws_size;
  const float* nf   = (const float*)d_in[0];
  const int*   src  = (const int*)d_in[1];
  const int*   dst  = (const int*)d_in[2];
  const float* ts   = (const float*)d_in[3];
  const float* ef   = (const float*)d_in[4];
  const float* Wnp  = (const float*)d_in[5];
  const float* bnp  = (const float*)d_in[6];
  const float* Wmsg = (const float*)d_in[7];
  const float* bmsg = (const float*)d_in[8];
  const float* Wih  = (const float*)d_in[9];
  const float* Whh  = (const float*)d_in[10];
  const float* bih  = (const float*)d_in[11];
  const float* bhh  = (const float*)d_in[12];
  const float* w0   = (const float*)d_in[13];
  const float* b0   = (const float*)d_in[14];
  const float* tW   = (const float*)d_in[15];
  const float* tB   = (const float*)d_in[16];
  const float* Wg   = (const float*)d_in[17];
  const float* bg   = (const float*)d_in[18];
  const float* Wp   = (const float*)d_in[19];
  const float* bp   = (const float*)d_in[20];

  double* partials = (double*)((char*)d_ws + WS_PART_OFF);
  float*  states   = (float*)((char*)d_ws + WS_STATES_OFF);
  int*    done     = (int*)((char*)d_ws + WS_DONE_OFF);
  float*  out      = (float*)d_out;

  hipMemsetAsync(done, 0, NEDGE*sizeof(int), stream);
  k_main<<<NEDGE + NB_BULK, 256, 0, stream>>>(
      nf, src, dst, ts, ef, Wnp, bnp, Wmsg, bmsg,
      Wih, Whh, bih, bhh, w0, b0, tW, tB, Wg, bg,
      partials, states, done);
  k_fin<<<1, 256, 0, stream>>>(nf, src, dst, Wnp, bnp, Wg, bg, Wp, bp, partials, states, out);
}

// Round 6
// 50.472 us; speedup vs baseline: 1.6083x; 1.0058x over previous
//
#include <hip/hip_runtime.h>
#include <math.h>

#define N_NODES 100000
#define NEDGE 64
#define NFEAT 11
#define EFEAT 30
#define MEM 64
#define TD 16
#define MSGIN 174
#define G3 192
#define NB_BULK 391
#define NSLOT 128

// ws layout (bytes)
#define WS_PART_OFF   0
#define WS_STATES_OFF ((size_t)NB_BULK*12*sizeof(double))                   // 37536
#define WS_DONE_OFF   (WS_STATES_OFF + (size_t)NSLOT*MEM*sizeof(float))     // +32768

__device__ __forceinline__ float sigmoidf_(float x) { return 1.f/(1.f+expf(-x)); }

// ================= k0: reset done flags (replaces 39us fillBufferAligned) =================
__global__ __launch_bounds__(64) void k_zero(int* __restrict__ done)
{
  done[threadIdx.x] = 0;
}

// ================= k1: 64 edge blocks + 391 bulk blocks =================
__global__ __launch_bounds__(256) void k_main(
    const float* __restrict__ nf, const int* __restrict__ src, const int* __restrict__ dst,
    const float* __restrict__ ts, const float* __restrict__ ef,
    const float* __restrict__ Wnp, const float* __restrict__ bnp,
    const float* __restrict__ Wmsg, const float* __restrict__ bmsg,
    const float* __restrict__ Wih, const float* __restrict__ Whh,
    const float* __restrict__ bih, const float* __restrict__ bhh,
    const float* __restrict__ w0, const float* __restrict__ b0,
    const float* __restrict__ tW, const float* __restrict__ tB,
    const float* __restrict__ Wg, const float* __restrict__ bg,
    double* __restrict__ partials, float* __restrict__ states,
    int* __restrict__ done)
{
  int t = threadIdx.x;
  int bid = blockIdx.x;

  // ---------------- bulk blocks: one 256-row tile each ----------------
  if (bid >= NEDGE) {
    __shared__ float sG[NFEAT];
    __shared__ float sCl;
    __shared__ float sTile[256*NFEAT];
    __shared__ float sW[4][12];
    int b = bid - NEDGE;
    if (t < NFEAT) { float a = 0.f; for (int j=0;j<MEM;j++) a += Wnp[t*MEM+j]*Wg[j]; sG[t] = a; }
    if (t == NFEAT) { float a = bg[0]; for (int j=0;j<MEM;j++) a += bnp[j]*Wg[j]; sCl = a; }
    __syncthreads();
    float accE = 0.f, accS[NFEAT];
    #pragma unroll
    for (int k=0;k<NFEAT;k++) accS[k]=0.f;
    int base = b*256;
    {
      int nrows = min(256, N_NODES - base);
      for (int i = t; i < nrows*NFEAT; i += 256) sTile[i] = nf[(long)base*NFEAT + i];
      __syncthreads();
      if (t < nrows) {
        float x[NFEAT];
        #pragma unroll
        for (int k=0;k<NFEAT;k++) x[k] = sTile[t*NFEAT+k];
        float l = sCl;
        #pragma unroll
        for (int k=0;k<NFEAT;k++) l += x[k]*sG[k];
        float e = expf(l);
        accE += e;
        #pragma unroll
        for (int k=0;k<NFEAT;k++) accS[k] += e*x[k];
      }
    }
    #pragma unroll
    for (int off=32; off; off>>=1) {
      accE += __shfl_down(accE, off);
      #pragma unroll
      for (int k=0;k<NFEAT;k++) accS[k] += __shfl_down(accS[k], off);
    }
    int wv = t>>6;
    if ((t&63)==0) { sW[wv][0]=accE; for (int k=0;k<NFEAT;k++) sW[wv][1+k]=accS[k]; }
    __syncthreads();
    if (t < 12) {
      double d = (double)sW[0][t] + (double)sW[1][t] + (double)sW[2][t] + (double)sW[3][t];
      partials[b*12 + t] = d;   // published to k_fin at kernel boundary
    }
    return;
  }

  // ---------------- edge block (R2-proven protocol, verbatim) ----------------
  __shared__ int sEp[128], sMap[128], sFirst[128];
  __shared__ float sX[176];
  __shared__ float sMsg[MEM];
  __shared__ float sGi[G3], sGhs[G3], sGhd[G3];
  __shared__ float sNewS[MEM];

  if (t < 64) sEp[t] = src[t];
  else if (t < 128) sEp[t] = dst[t-64];
  __syncthreads();
  if (t < 128) {
    int id = sEp[t]; int fo = t; int fe = t & 63;
    for (int i = 0; i < 128; i++) {
      if (sEp[i] == id) { if (i < fo) fo = i; int ei = i & 63; if (ei < fe) fe = ei; }
    }
    sMap[t] = fo; sFirst[t] = fe;
  }
  __syncthreads();

  int e = bid;
  int ss = sMap[e], dd = sMap[64+e];

  if (t < e) {
    bool c = (sMap[t]==ss) || (sMap[t]==dd) || (sMap[64+t]==ss) || (sMap[64+t]==dd);
    if (c) {
      while (!__hip_atomic_load(&done[t], __ATOMIC_ACQUIRE, __HIP_MEMORY_SCOPE_AGENT))
        __builtin_amdgcn_s_sleep(2);
    }
  }
  __syncthreads();

  bool initS = (sFirst[ss] == e);
  bool initD = (sFirst[dd] == e);
  if (t < 64) {
    float v;
    if (initS) {
      const float* row = nf + (long)sEp[ss]*NFEAT;
      v = bnp[t];
      #pragma unroll
      for (int k = 0; k < NFEAT; k++) v += row[k]*Wnp[k*MEM + t];
    } else {
      v = __hip_atomic_load(&states[ss*MEM + t], __ATOMIC_RELAXED, __HIP_MEMORY_SCOPE_AGENT);
    }
    sX[t] = v;
  } else if (t < 128) {
    int j = t - 64; float v;
    if (initD) {
      const float* row = nf + (long)sEp[dd]*NFEAT;
      v = bnp[j];
      #pragma unroll
      for (int k = 0; k < NFEAT; k++) v += row[k]*Wnp[k*MEM + j];
    } else {
      v = __hip_atomic_load(&states[dd*MEM + j], __ATOMIC_RELAXED, __HIP_MEMORY_SCOPE_AGENT);
    }
    sX[t] = v;
  } else if (t < 158) {
    sX[t] = ef[e*EFEAT + (t-128)];
  } else if (t < 174) {
    int q = t - 158; float tt = ts[e];
    sX[t] = (q == 0) ? (tt*w0[0] + b0[0]) : sinf(tt*tW[q-1] + tB[q-1]);
  } else if (t < 176) sX[t] = 0.f;
  __syncthreads();

  {
    int mj = t >> 2, mg = t & 3, mk0 = mg*44;
    float w[44];
    #pragma unroll
    for (int kk = 0; kk < 44; kk++) {
      int k = mk0 + kk;
      w[kk] = (k < MSGIN) ? Wmsg[k*MEM + mj] : 0.f;
    }
    float a0=0.f,a1=0.f,a2=0.f,a3=0.f;
    #pragma unroll
    for (int kk=0; kk<44; kk+=4) {
      a0 += w[kk]  * sX[mk0+kk];
      a1 += w[kk+1]* sX[mk0+kk+1];
      a2 += w[kk+2]* sX[mk0+kk+2];
      a3 += w[kk+3]* sX[mk0+kk+3];
    }
    float a = (a0+a1)+(a2+a3);
    a += __shfl_xor(a,1);
    a += __shfl_xor(a,2);
    if (mg == 0) sMsg[mj] = fmaxf(a + bmsg[mj], 0.f);
  }
  __syncthreads();

  if (t < G3) {
    const float4* wi4 = (const float4*)(Wih + t*MEM);
    const float4* wh4 = (const float4*)(Whh + t*MEM);
    float a0=0.f,a1=0.f,a2=0.f,a3=0.f;
    float b0v=0.f,b1v=0.f,b2v=0.f,b3v=0.f;
    float c0=0.f,c1=0.f,c2=0.f,c3=0.f;
    #pragma unroll
    for (int k = 0; k < MEM; k += 4) {
      float4 vi = wi4[k>>2];
      float4 vh = wh4[k>>2];
      a0 += vi.x*sMsg[k];   a1 += vi.y*sMsg[k+1];   a2 += vi.z*sMsg[k+2];   a3 += vi.w*sMsg[k+3];
      b0v+= vh.x*sX[k];     b1v+= vh.y*sX[k+1];     b2v+= vh.z*sX[k+2];     b3v+= vh.w*sX[k+3];
      c0 += vh.x*sX[64+k];  c1 += vh.y*sX[64+k+1];  c2 += vh.z*sX[64+k+2];  c3 += vh.w*sX[64+k+3];
    }
    sGi[t]  = (a0+a1)+(a2+a3) + bih[t];
    sGhs[t] = (b0v+b1v)+(b2v+b3v) + bhh[t];
    sGhd[t] = (c0+c1)+(c2+c3) + bhh[t];
  }
  __syncthreads();

  if (ss != dd) {
    if (t < 128) {
      int j = t & 63;
      bool iss = t < 64;
      float h = sX[t];
      const float* gh = iss ? sGhs : sGhd;
      float r = sigmoidf_(sGi[j] + gh[j]);
      float z = sigmoidf_(sGi[64+j] + gh[64+j]);
      float n = tanhf(sGi[128+j] + r*gh[128+j]);
      float hn = (1.f - z)*n + z*h;
      int slot = iss ? ss : dd;
      __hip_atomic_store(&states[slot*MEM + j], hn, __ATOMIC_RELAXED, __HIP_MEMORY_SCOPE_AGENT);
    }
  } else {
    if (t < 64) {
      float h = sX[t];
      float r = sigmoidf_(sGi[t] + sGhs[t]);
      float z = sigmoidf_(sGi[64+t] + sGhs[64+t]);
      float n = tanhf(sGi[128+t] + r*sGhs[128+t]);
      sNewS[t] = (1.f - z)*n + z*h;
    }
    __syncthreads();
    if (t < G3) {
      const float4* wh4 = (const float4*)(Whh + t*MEM);
      float b0v=0.f,b1v=0.f,b2v=0.f,b3v=0.f;
      #pragma unroll
      for (int k = 0; k < MEM; k += 4) {
        float4 vh = wh4[k>>2];
        b0v += vh.x*sNewS[k];  b1v += vh.y*sNewS[k+1];
        b2v += vh.z*sNewS[k+2]; b3v += vh.w*sNewS[k+3];
      }
      sGhd[t] = (b0v+b1v)+(b2v+b3v) + bhh[t];
    }
    __syncthreads();
    if (t < 64) {
      float h = sNewS[t];
      float r = sigmoidf_(sGi[t] + sGhd[t]);
      float z = sigmoidf_(sGi[64+t] + sGhd[64+t]);
      float n = tanhf(sGi[128+t] + r*sGhd[128+t]);
      float hn = (1.f - z)*n + z*h;
      __hip_atomic_store(&states[ss*MEM + t], hn, __ATOMIC_RELAXED, __HIP_MEMORY_SCOPE_AGENT);
    }
  }
  __threadfence();
  __syncthreads();
  if (t == 0) __hip_atomic_store(&done[e], 1, __ATOMIC_RELEASE, __HIP_MEMORY_SCOPE_AGENT);
}

// ================= k2: fully parallel readout + combine (1 block) =================
__global__ __launch_bounds__(256) void k_fin(
    const float* __restrict__ nf, const int* __restrict__ src, const int* __restrict__ dst,
    const float* __restrict__ Wnp, const float* __restrict__ bnp,
    const float* __restrict__ Wg, const float* __restrict__ bg,
    const float* __restrict__ Wp, const float* __restrict__ bp,
    const double* __restrict__ partials, const float* __restrict__ states,
    float* __restrict__ out)
{
  __shared__ float sH[NSLOT][MEM];      // 32 KB final states
  __shared__ float sWp[MEM][MEM];       // 16 KB
  __shared__ float sWnp[NFEAT][MEM];    // 2.75 KB
  __shared__ float sNF[NSLOT][12];      // nf rows of endpoints
  __shared__ int sEp[NSLOT], sMap[NSLOT];
  __shared__ float sWg[MEM], sBp[MEM], sBnp[MEM];
  __shared__ float sE0[4], sE1[4], sS0[4][NFEAT], sQ[4][MEM];
  __shared__ double sA[4][12];
  __shared__ double sTot[12];
  __shared__ double sM[MEM];
  __shared__ double sScal[3];           // E0tot, den1

  int t = threadIdx.x, lane = t & 63, wv = t >> 6;
  float bg0 = bg[0];

  // ---- stage (parallel) ----
  if (t < 64) sEp[t] = src[t];
  else if (t < 128) sEp[t] = dst[t-64];
  if (t < MEM) { sWg[t] = Wg[t]; sBp[t] = bp[t]; sBnp[t] = bnp[t]; }
  for (int i = t; i < MEM*MEM; i += 256) sWp[i>>6][i&63] = Wp[i];
  for (int i = t; i < NFEAT*MEM; i += 256) sWnp[i>>6][i&63] = Wnp[i];
  for (int i = t; i < NSLOT*MEM; i += 256) sH[i>>6][i&63] = states[i];
  __syncthreads();
  if (t < 128) {
    int id = sEp[t]; int fo = t;
    for (int i = 0; i < 128; i++) if (sEp[i] == id) { fo = i; break; }
    sMap[t] = fo;
  }
  for (int i = t; i < NSLOT*NFEAT; i += 256) {
    int s = i / NFEAT, k = i - s*NFEAT;
    sNF[s][k] = nf[(long)sEp[s]*NFEAT + k];
  }
  __syncthreads();

  // ---- A: bulk partials reduction (391 x 12 doubles) ----
  {
    double v[12];
    #pragma unroll
    for (int k=0;k<12;k++) {
      double a = partials[t*12 + k];                       // t < 256 < 391
      if (t + 256 < NB_BULK) a += partials[(t+256)*12 + k];
      v[k] = a;
    }
    #pragma unroll
    for (int off=32; off; off>>=1) {
      #pragma unroll
      for (int k=0;k<12;k++) v[k] += __shfl_down(v[k], off);
    }
    if (lane == 0) { for (int k=0;k<12;k++) sA[wv][k] = v[k]; }
  }

  // ---- B: per-slot e0/e1/q (wave wv handles slots it*4+wv) ----
  {
    float accE0 = 0.f, accE1 = 0.f, accQ = 0.f, accS0[NFEAT];
    #pragma unroll
    for (int k=0;k<NFEAT;k++) accS0[k] = 0.f;
    for (int it = 0; it < 32; it++) {
      int s = it*4 + wv;
      bool used = (sMap[s] == s);
      float h0 = sBnp[lane];
      #pragma unroll
      for (int k=0;k<NFEAT;k++) h0 += sNF[s][k]*sWnp[k][lane];
      float v0 = h0 * sWg[lane];
      float v1 = sH[s][lane] * sWg[lane];
      #pragma unroll
      for (int off=32; off; off>>=1) { v0 += __shfl_xor(v0, off); v1 += __shfl_xor(v1, off); }
      float e0 = used ? expf(v0 + bg0) : 0.f;
      float e1 = used ? expf(v1 + bg0) : 0.f;
      accE0 += e0; accE1 += e1;
      #pragma unroll
      for (int k=0;k<NFEAT;k++) accS0[k] += e0*sNF[s][k];
      accQ += e1 * sH[s][lane];
    }
    if (lane == 0) { sE0[wv] = accE0; sE1[wv] = accE1; for (int k=0;k<NFEAT;k++) sS0[wv][k] = accS0[k]; }
    sQ[wv][lane] = accQ;
  }
  __syncthreads();

  if (t < 12) sTot[t] = sA[0][t] + sA[1][t] + sA[2][t] + sA[3][t];
  if (t == 12) sScal[0] = (double)sE0[0] + (double)sE0[1] + (double)sE0[2] + (double)sE0[3];
  if (t == 13) sScal[1] = (double)sE1[0] + (double)sE1[1] + (double)sE1[2] + (double)sE1[3];
  __syncthreads();

  // ---- C: combine in double ----
  if (t < MEM) {
    double Eall = sTot[0] - sScal[0];
    double a = Eall * (double)sBnp[t];
    #pragma unroll
    for (int k=0;k<NFEAT;k++) {
      double S0k = (double)sS0[0][k] + (double)sS0[1][k] + (double)sS0[2][k] + (double)sS0[3][k];
      a += (sTot[1+k] - S0k) * (double)sWnp[k][t];
    }
    double q = (double)sQ[0][t] + (double)sQ[1][t] + (double)sQ[2][t] + (double)sQ[3][t];
    sM[t] = a + q;
  }
  __syncthreads();
  if (t < MEM) {
    double Eall = sTot[0] - sScal[0];
    double den = Eall + sScal[1];
    double a = 0.0;
    for (int m=0;m<MEM;m++) a += sM[m] * (double)sWp[m][t];
    out[t] = (float)(a/den + (double)sBp[t]);
  }
}

extern "C" void kernel_launch(void* const* d_in, const int* in_sizes, int n_in,
                              void* d_out, int out_size, void* d_ws, size_t ws_size,
                              hipStream_t stream) {
  (void)in_sizes; (void)n_in; (void)out_size; (void)ws_size;
  const float* nf   = (const float*)d_in[0];
  const int*   src  = (const int*)d_in[1];
  const int*   dst  = (const int*)d_in[2];
  const float* ts   = (const float*)d_in[3];
  const float* ef   = (const float*)d_in[4];
  const float* Wnp  = (const float*)d_in[5];
  const float* bnp  = (const float*)d_in[6];
  const float* Wmsg = (const float*)d_in[7];
  const float* bmsg = (const float*)d_in[8];
  const float* Wih  = (const float*)d_in[9];
  const float* Whh  = (const float*)d_in[10];
  const float* bih  = (const float*)d_in[11];
  const float* bhh  = (const float*)d_in[12];
  const float* w0   = (const float*)d_in[13];
  const float* b0   = (const float*)d_in[14];
  const float* tW   = (const float*)d_in[15];
  const float* tB   = (const float*)d_in[16];
  const float* Wg   = (const float*)d_in[17];
  const float* bg   = (const float*)d_in[18];
  const float* Wp   = (const float*)d_in[19];
  const float* bp   = (const float*)d_in[20];

  double* partials = (double*)((char*)d_ws + WS_PART_OFF);
  float*  states   = (float*)((char*)d_ws + WS_STATES_OFF);
  int*    done     = (int*)((char*)d_ws + WS_DONE_OFF);
  float*  out      = (float*)d_out;

  k_zero<<<1, 64, 0, stream>>>(done);
  k_main<<<NEDGE + NB_BULK, 256, 0, stream>>>(
      nf, src, dst, ts, ef, Wnp, bnp, Wmsg, bmsg,
      Wih, Whh, bih, bhh, w0, b0, tW, tB, Wg, bg,
      partials, states, done);
  k_fin<<<1, 256, 0, stream>>>(nf, src, dst, Wnp, bnp, Wg, bg, Wp, bp, partials, states, out);
}

// Round 7
// 39.063 us; speedup vs baseline: 2.0781x; 1.2921x over previous
//
#include <hip/hip_runtime.h>
#include <math.h>

#define N_NODES 100000
#define NEDGE 64
#define NFEAT 11
#define EFEAT 30
#define MEM 64
#define TD 16
#define MSGIN 174
#define G3 192
#define NB_BULK 391
#define NSLOT 128
#define DONE_MAGIC 0x5A17E000

// ws layout (bytes)
#define WS_PART_OFF   0
#define WS_STATES_OFF ((size_t)NB_BULK*12*sizeof(double))                   // 37536 (16B-aligned)
#define WS_DONE_OFF   (WS_STATES_OFF + (size_t)NSLOT*MEM*sizeof(float))

__device__ __forceinline__ float sigmoidf_(float x) { return 1.f/(1.f+expf(-x)); }

// ================= k1: 64 edge blocks + 391 bulk blocks =================
__global__ __launch_bounds__(256) void k_main(
    const float* __restrict__ nf, const int* __restrict__ src, const int* __restrict__ dst,
    const float* __restrict__ ts, const float* __restrict__ ef,
    const float* __restrict__ Wnp, const float* __restrict__ bnp,
    const float* __restrict__ Wmsg, const float* __restrict__ bmsg,
    const float* __restrict__ Wih, const float* __restrict__ Whh,
    const float* __restrict__ bih, const float* __restrict__ bhh,
    const float* __restrict__ w0, const float* __restrict__ b0,
    const float* __restrict__ tW, const float* __restrict__ tB,
    const float* __restrict__ Wg, const float* __restrict__ bg,
    double* __restrict__ partials, float* __restrict__ states,
    int* __restrict__ done)
{
  int t = threadIdx.x;
  int bid = blockIdx.x;

  // ---------------- bulk blocks: one 256-row tile, no LDS staging ----------------
  if (bid >= NEDGE) {
    __shared__ float sG[NFEAT];
    __shared__ float sCl;
    __shared__ float sW[4][12];
    int b = bid - NEDGE;
    if (t < NFEAT) {
      float a = 0.f;
      #pragma unroll
      for (int j=0;j<MEM;j++) a += Wnp[t*MEM+j]*Wg[j];
      sG[t] = a;
    }
    if (t == NFEAT) {
      float a = bg[0];
      #pragma unroll
      for (int j=0;j<MEM;j++) a += bnp[j]*Wg[j];
      sCl = a;
    }
    __syncthreads();
    float accE = 0.f, accS[NFEAT];
    #pragma unroll
    for (int k=0;k<NFEAT;k++) accS[k]=0.f;
    int row = b*256 + t;
    if (row < N_NODES) {
      float x[NFEAT];
      #pragma unroll
      for (int k=0;k<NFEAT;k++) x[k] = nf[(long)row*NFEAT + k];   // 11 independent loads
      float l = sCl;
      #pragma unroll
      for (int k=0;k<NFEAT;k++) l += x[k]*sG[k];
      float e = expf(l);
      accE = e;
      #pragma unroll
      for (int k=0;k<NFEAT;k++) accS[k] = e*x[k];
    }
    #pragma unroll
    for (int off=32; off; off>>=1) {
      accE += __shfl_down(accE, off);
      #pragma unroll
      for (int k=0;k<NFEAT;k++) accS[k] += __shfl_down(accS[k], off);
    }
    int wv = t>>6;
    if ((t&63)==0) { sW[wv][0]=accE; for (int k=0;k<NFEAT;k++) sW[wv][1+k]=accS[k]; }
    __syncthreads();
    if (t < 12) {
      double d = (double)sW[0][t] + (double)sW[1][t] + (double)sW[2][t] + (double)sW[3][t];
      partials[b*12 + t] = d;   // published to k_fin at kernel boundary
    }
    return;
  }

  // ---------------- edge block (proven protocol; release value = MAGIC|e) ----------------
  __shared__ int sEp[128], sMap[128], sFirst[128];
  __shared__ float sX[176];
  __shared__ float sMsg[MEM];
  __shared__ float sGi[G3], sGhs[G3], sGhd[G3];
  __shared__ float sNewS[MEM];

  if (t < 64) sEp[t] = src[t];
  else if (t < 128) sEp[t] = dst[t-64];
  __syncthreads();
  if (t < 128) {
    int id = sEp[t]; int fo = t; int fe = t & 63;
    for (int i = 0; i < 128; i++) {
      if (sEp[i] == id) { if (i < fo) fo = i; int ei = i & 63; if (ei < fe) fe = ei; }
    }
    sMap[t] = fo; sFirst[t] = fe;
  }
  __syncthreads();

  int e = bid;
  int ss = sMap[e], dd = sMap[64+e];

  if (t < e) {
    bool c = (sMap[t]==ss) || (sMap[t]==dd) || (sMap[64+t]==ss) || (sMap[64+t]==dd);
    if (c) {
      int want = DONE_MAGIC | t;
      while (__hip_atomic_load(&done[t], __ATOMIC_ACQUIRE, __HIP_MEMORY_SCOPE_AGENT) != want)
        __builtin_amdgcn_s_sleep(2);
    }
  }
  __syncthreads();

  bool initS = (sFirst[ss] == e);
  bool initD = (sFirst[dd] == e);
  if (t < 64) {
    float v;
    if (initS) {
      const float* row = nf + (long)sEp[ss]*NFEAT;
      v = bnp[t];
      #pragma unroll
      for (int k = 0; k < NFEAT; k++) v += row[k]*Wnp[k*MEM + t];
    } else {
      v = __hip_atomic_load(&states[ss*MEM + t], __ATOMIC_RELAXED, __HIP_MEMORY_SCOPE_AGENT);
    }
    sX[t] = v;
  } else if (t < 128) {
    int j = t - 64; float v;
    if (initD) {
      const float* row = nf + (long)sEp[dd]*NFEAT;
      v = bnp[j];
      #pragma unroll
      for (int k = 0; k < NFEAT; k++) v += row[k]*Wnp[k*MEM + j];
    } else {
      v = __hip_atomic_load(&states[dd*MEM + j], __ATOMIC_RELAXED, __HIP_MEMORY_SCOPE_AGENT);
    }
    sX[t] = v;
  } else if (t < 158) {
    sX[t] = ef[e*EFEAT + (t-128)];
  } else if (t < 174) {
    int q = t - 158; float tt = ts[e];
    sX[t] = (q == 0) ? (tt*w0[0] + b0[0]) : sinf(tt*tW[q-1] + tB[q-1]);
  } else if (t < 176) sX[t] = 0.f;
  __syncthreads();

  {
    int mj = t >> 2, mg = t & 3, mk0 = mg*44;
    float w[44];
    #pragma unroll
    for (int kk = 0; kk < 44; kk++) {
      int k = mk0 + kk;
      w[kk] = (k < MSGIN) ? Wmsg[k*MEM + mj] : 0.f;
    }
    float a0=0.f,a1=0.f,a2=0.f,a3=0.f;
    #pragma unroll
    for (int kk=0; kk<44; kk+=4) {
      a0 += w[kk]  * sX[mk0+kk];
      a1 += w[kk+1]* sX[mk0+kk+1];
      a2 += w[kk+2]* sX[mk0+kk+2];
      a3 += w[kk+3]* sX[mk0+kk+3];
    }
    float a = (a0+a1)+(a2+a3);
    a += __shfl_xor(a,1);
    a += __shfl_xor(a,2);
    if (mg == 0) sMsg[mj] = fmaxf(a + bmsg[mj], 0.f);
  }
  __syncthreads();

  if (t < G3) {
    const float4* wi4 = (const float4*)(Wih + t*MEM);
    const float4* wh4 = (const float4*)(Whh + t*MEM);
    float a0=0.f,a1=0.f,a2=0.f,a3=0.f;
    float b0v=0.f,b1v=0.f,b2v=0.f,b3v=0.f;
    float c0=0.f,c1=0.f,c2=0.f,c3=0.f;
    #pragma unroll
    for (int k = 0; k < MEM; k += 4) {
      float4 vi = wi4[k>>2];
      float4 vh = wh4[k>>2];
      a0 += vi.x*sMsg[k];   a1 += vi.y*sMsg[k+1];   a2 += vi.z*sMsg[k+2];   a3 += vi.w*sMsg[k+3];
      b0v+= vh.x*sX[k];     b1v+= vh.y*sX[k+1];     b2v+= vh.z*sX[k+2];     b3v+= vh.w*sX[k+3];
      c0 += vh.x*sX[64+k];  c1 += vh.y*sX[64+k+1];  c2 += vh.z*sX[64+k+2];  c3 += vh.w*sX[64+k+3];
    }
    sGi[t]  = (a0+a1)+(a2+a3) + bih[t];
    sGhs[t] = (b0v+b1v)+(b2v+b3v) + bhh[t];
    sGhd[t] = (c0+c1)+(c2+c3) + bhh[t];
  }
  __syncthreads();

  if (ss != dd) {
    if (t < 128) {
      int j = t & 63;
      bool iss = t < 64;
      float h = sX[t];
      const float* gh = iss ? sGhs : sGhd;
      float r = sigmoidf_(sGi[j] + gh[j]);
      float z = sigmoidf_(sGi[64+j] + gh[64+j]);
      float n = tanhf(sGi[128+j] + r*gh[128+j]);
      float hn = (1.f - z)*n + z*h;
      int slot = iss ? ss : dd;
      __hip_atomic_store(&states[slot*MEM + j], hn, __ATOMIC_RELAXED, __HIP_MEMORY_SCOPE_AGENT);
    }
  } else {
    if (t < 64) {
      float h = sX[t];
      float r = sigmoidf_(sGi[t] + sGhs[t]);
      float z = sigmoidf_(sGi[64+t] + sGhs[64+t]);
      float n = tanhf(sGi[128+t] + r*sGhs[128+t]);
      sNewS[t] = (1.f - z)*n + z*h;
    }
    __syncthreads();
    if (t < G3) {
      const float4* wh4 = (const float4*)(Whh + t*MEM);
      float b0v=0.f,b1v=0.f,b2v=0.f,b3v=0.f;
      #pragma unroll
      for (int k = 0; k < MEM; k += 4) {
        float4 vh = wh4[k>>2];
        b0v += vh.x*sNewS[k];  b1v += vh.y*sNewS[k+1];
        b2v += vh.z*sNewS[k+2]; b3v += vh.w*sNewS[k+3];
      }
      sGhd[t] = (b0v+b1v)+(b2v+b3v) + bhh[t];
    }
    __syncthreads();
    if (t < 64) {
      float h = sNewS[t];
      float r = sigmoidf_(sGi[t] + sGhd[t]);
      float z = sigmoidf_(sGi[64+t] + sGhd[64+t]);
      float n = tanhf(sGi[128+t] + r*sGhd[128+t]);
      float hn = (1.f - z)*n + z*h;
      __hip_atomic_store(&states[ss*MEM + t], hn, __ATOMIC_RELAXED, __HIP_MEMORY_SCOPE_AGENT);
    }
  }
  __threadfence();
  __syncthreads();
  if (t == 0) __hip_atomic_store(&done[e], DONE_MAGIC | e, __ATOMIC_RELEASE, __HIP_MEMORY_SCOPE_AGENT);
}

// ================= k2: wide-staged parallel readout + combine (1 block, 1024 thr) =================
__global__ __launch_bounds__(1024) void k_fin(
    const float* __restrict__ nf, const int* __restrict__ src, const int* __restrict__ dst,
    const float* __restrict__ Wnp, const float* __restrict__ bnp,
    const float* __restrict__ Wg, const float* __restrict__ bg,
    const float* __restrict__ Wp, const float* __restrict__ bp,
    const double* __restrict__ partials, const float* __restrict__ states,
    int* __restrict__ done, float* __restrict__ out)
{
  __shared__ __align__(16) float sH[NSLOT][MEM];      // 32 KB
  __shared__ __align__(16) float sWp[MEM][MEM];       // 16 KB
  __shared__ __align__(16) float sWnp[NFEAT][MEM];    // 2.75 KB
  __shared__ float sNF[NSLOT][12];
  __shared__ int sEp[NSLOT], sMap[NSLOT];
  __shared__ float sWg[MEM], sBp[MEM], sBnp[MEM];
  __shared__ float sE0[16], sE1[16], sS0[16][NFEAT], sQ[16][MEM];
  __shared__ double sA[16][12];
  __shared__ double sTot[12];
  __shared__ double sM[MEM];
  __shared__ double sScal[2];

  int t = threadIdx.x, lane = t & 63, wv = t >> 6;
  float bg0 = bg[0];

  // ---- wide staging: all misses issued in parallel ----
  if (t < 64) sEp[t] = src[t];
  else if (t < 128) sEp[t] = dst[t-64];
  if (t >= 128 && t < 192) { int j=t-128; sWg[j]=Wg[j]; sBp[j]=bp[j]; sBnp[j]=bnp[j]; }
  ((float4*)&sH[0][0])[t]        = ((const float4*)states)[t];
  ((float4*)&sH[0][0])[t+1024]   = ((const float4*)states)[t+1024];
  ((float4*)&sWp[0][0])[t]       = ((const float4*)Wp)[t];
  if (t < 176) ((float4*)&sWnp[0][0])[t] = ((const float4*)Wnp)[t];
  double v[12];
  #pragma unroll
  for (int k=0;k<12;k++) v[k] = (t < NB_BULK) ? partials[t*12+k] : 0.0;
  __syncthreads();
  if (t < 128) {
    int id = sEp[t]; int fo = t;
    for (int i = 0; i < 128; i++) if (sEp[i] == id) { fo = i; break; }
    sMap[t] = fo;
  }
  for (int i = t; i < NSLOT*NFEAT; i += 1024) {
    int s = i / NFEAT, k = i - s*NFEAT;
    sNF[s][k] = nf[(long)sEp[s]*NFEAT + k];
  }
  // ---- A: bulk partials butterfly (391 rows over 16 waves) ----
  #pragma unroll
  for (int off=32; off; off>>=1) {
    #pragma unroll
    for (int k=0;k<12;k++) v[k] += __shfl_down(v[k], off);
  }
  if (lane == 0) { for (int k=0;k<12;k++) sA[wv][k] = v[k]; }
  __syncthreads();

  // ---- B: per-slot e0/e1/q — wave wv handles slots it*16+wv (8 iters) ----
  {
    float accE0 = 0.f, accE1 = 0.f, accQ = 0.f, accS0[NFEAT];
    #pragma unroll
    for (int k=0;k<NFEAT;k++) accS0[k] = 0.f;
    for (int it = 0; it < 8; it++) {
      int s = it*16 + wv;
      bool used = (sMap[s] == s);
      float h0 = sBnp[lane];
      #pragma unroll
      for (int k=0;k<NFEAT;k++) h0 += sNF[s][k]*sWnp[k][lane];
      float v0 = h0 * sWg[lane];
      float v1 = sH[s][lane] * sWg[lane];
      #pragma unroll
      for (int off=32; off; off>>=1) { v0 += __shfl_xor(v0, off); v1 += __shfl_xor(v1, off); }
      float e0 = used ? expf(v0 + bg0) : 0.f;
      float e1 = used ? expf(v1 + bg0) : 0.f;
      accE0 += e0; accE1 += e1;
      #pragma unroll
      for (int k=0;k<NFEAT;k++) accS0[k] += e0*sNF[s][k];
      accQ += e1 * sH[s][lane];
    }
    if (lane == 0) { sE0[wv] = accE0; sE1[wv] = accE1; for (int k=0;k<NFEAT;k++) sS0[wv][k] = accS0[k]; }
    sQ[wv][lane] = accQ;
  }
  __syncthreads();

  if (t < 12) {
    double d = 0.0;
    #pragma unroll
    for (int w=0;w<16;w++) d += sA[w][t];
    sTot[t] = d;
  }
  if (t == 12) { double d=0.0; for (int w=0;w<16;w++) d += (double)sE0[w]; sScal[0] = d; }
  if (t == 13) { double d=0.0; for (int w=0;w<16;w++) d += (double)sE1[w]; sScal[1] = d; }
  __syncthreads();

  // ---- C: combine in double ----
  if (t < MEM) {
    double Eall = sTot[0] - sScal[0];
    double a = Eall * (double)sBnp[t];
    #pragma unroll
    for (int k=0;k<NFEAT;k++) {
      double S0k = 0.0;
      #pragma unroll
      for (int w=0;w<16;w++) S0k += (double)sS0[w][k];
      a += (sTot[1+k] - S0k) * (double)sWnp[k][t];
    }
    double q = 0.0;
    #pragma unroll
    for (int w=0;w<16;w++) q += (double)sQ[w][t];
    sM[t] = a + q;
  }
  __syncthreads();
  if (t < MEM) {
    double Eall = sTot[0] - sScal[0];
    double den = Eall + sScal[1];
    double a = 0.0;
    for (int m=0;m<MEM;m++) a += sM[m] * (double)sWp[m][t];
    out[t] = (float)(a/den + (double)sBp[t]);
  }
  // reset done flags for the next replay (magic-keyed protocol: 0 != MAGIC|e, poison != MAGIC|e)
  if (t < NEDGE) done[t] = 0;
}

extern "C" void kernel_launch(void* const* d_in, const int* in_sizes, int n_in,
                              void* d_out, int out_size, void* d_ws, size_t ws_size,
                              hipStream_t stream) {
  (void)in_sizes; (void)n_in; (void)out_size; (void)ws_size;
  const float* nf   = (const float*)d_in[0];
  const int*   src  = (const int*)d_in[1];
  const int*   dst  = (const int*)d_in[2];
  const float* ts   = (const float*)d_in[3];
  const float* ef   = (const float*)d_in[4];
  const float* Wnp  = (const float*)d_in[5];
  const float* bnp  = (const float*)d_in[6];
  const float* Wmsg = (const float*)d_in[7];
  const float* bmsg = (const float*)d_in[8];
  const float* Wih  = (const float*)d_in[9];
  const float* Whh  = (const float*)d_in[10];
  const float* bih  = (const float*)d_in[11];
  const float* bhh  = (const float*)d_in[12];
  const float* w0   = (const float*)d_in[13];
  const float* b0   = (const float*)d_in[14];
  const float* tW   = (const float*)d_in[15];
  const float* tB   = (const float*)d_in[16];
  const float* Wg   = (const float*)d_in[17];
  const float* bg   = (const float*)d_in[18];
  const float* Wp   = (const float*)d_in[19];
  const float* bp   = (const float*)d_in[20];

  double* partials = (double*)((char*)d_ws + WS_PART_OFF);
  float*  states   = (float*)((char*)d_ws + WS_STATES_OFF);
  int*    done     = (int*)((char*)d_ws + WS_DONE_OFF);
  float*  out      = (float*)d_out;

  k_main<<<NEDGE + NB_BULK, 256, 0, stream>>>(
      nf, src, dst, ts, ef, Wnp, bnp, Wmsg, bmsg,
      Wih, Whh, bih, bhh, w0, b0, tW, tB, Wg, bg,
      partials, states, done);
  k_fin<<<1, 1024, 0, stream>>>(nf, src, dst, Wnp, bnp, Wg, bg, Wp, bp,
                                partials, states, done, out);
}